// Round 8
// baseline (192.513 us; speedup 1.0000x reference)
//
#include <hip/hip_runtime.h>

// SFC model forward — bf16-compressed user-table gather.
//   out[b] = bias_w[0] + dot(user_w[user[b]], item_w[item[b]]) + freq_w[idx_emb[b], freq[b], 0]
//
// Evidence r1-r7: the gather mix is served at ~24G 128B-lines/s regardless of
// structure (random / sorted / masked / nt). A fp32 user row = 2 lines; bf16
// row = 1 aligned line. So: pass 1 converts user_w to bf16 in d_ws (streaming,
// ~70us), pass 2 gathers half the lines (~90us at the measured line rate).
// The 128MB bf16 table also fits the 256MB L3 -> duplicate gathers may hit.
// Accuracy: bf16 user x fp32 item dot, error ~2e-4 << 1.1e-2 threshold.

#define EMB_DIM 64

typedef float  f4  __attribute__((ext_vector_type(4)));
typedef unsigned short u8v __attribute__((ext_vector_type(8)));

__device__ __forceinline__ unsigned short f2bf(float x) {
    unsigned int u = __builtin_bit_cast(unsigned int, x);
    u += 0x7FFFu + ((u >> 16) & 1u);          // round-to-nearest-even
    return (unsigned short)(u >> 16);
}
__device__ __forceinline__ float bf2f(unsigned int h) {
    return __builtin_bit_cast(float, h << 16);
}

// pass 1: fp32 -> bf16, 8 elems/thread/iter, fully streaming
__global__ __launch_bounds__(256) void k_cvt(const float* __restrict__ src,
                                             unsigned short* __restrict__ dst,
                                             int n8) {
    const int i = blockIdx.x * blockDim.x + threadIdx.x;
    const int stride = gridDim.x * blockDim.x;
    for (int k = i; k < n8; k += stride) {
        const f4 a = *reinterpret_cast<const f4*>(src + (size_t)k * 8);
        const f4 b = *reinterpret_cast<const f4*>(src + (size_t)k * 8 + 4);
        u8v h;
        h.s0 = f2bf(a.x); h.s1 = f2bf(a.y); h.s2 = f2bf(a.z); h.s3 = f2bf(a.w);
        h.s4 = f2bf(b.x); h.s5 = f2bf(b.y); h.s6 = f2bf(b.z); h.s7 = f2bf(b.w);
        *reinterpret_cast<u8v*>(dst + (size_t)k * 8) = h;
    }
}

// pass 2: gather bf16 user rows (1 line each), fp32 item rows (cache-hot)
__global__ __launch_bounds__(256) void sfc_bf16(
    const int* __restrict__ user, const int* __restrict__ item,
    const int* __restrict__ freq, const int* __restrict__ idx_emb,
    const float* __restrict__ bias_w, const unsigned short* __restrict__ user_h,
    const float* __restrict__ item_w, const float* __restrict__ freq_w,
    float* __restrict__ out, int B)
{
    const int group = threadIdx.x >> 4;        // 16 groups of 16 lanes
    const int lane = threadIdx.x & 15;
    const int stride = (gridDim.x * blockDim.x) >> 4;
    const int start = blockIdx.x * 16 + group;
    const float bias0 = bias_w[0];

    int s = start;
    for (; s + 3 * stride < B; s += 4 * stride) {
        const int sa = s, sb = s + stride, sc = s + 2 * stride, sd = s + 3 * stride;
        const int ua = user[sa], ub = user[sb], uc = user[sc], ud = user[sd];
        const int ia = item[sa], ib = item[sb], ic = item[sc], id_ = item[sd];

        // bf16 user rows: lane covers elems [lane*4, lane*4+4) = 8 bytes
        const uint2 ha = *reinterpret_cast<const uint2*>(user_h + (size_t)ua * EMB_DIM + lane * 4);
        const uint2 hb = *reinterpret_cast<const uint2*>(user_h + (size_t)ub * EMB_DIM + lane * 4);
        const uint2 hc = *reinterpret_cast<const uint2*>(user_h + (size_t)uc * EMB_DIM + lane * 4);
        const uint2 hd = *reinterpret_cast<const uint2*>(user_h + (size_t)ud * EMB_DIM + lane * 4);
        const f4 iva = *reinterpret_cast<const f4*>(item_w + (size_t)ia * EMB_DIM + lane * 4);
        const f4 ivb = *reinterpret_cast<const f4*>(item_w + (size_t)ib * EMB_DIM + lane * 4);
        const f4 ivc = *reinterpret_cast<const f4*>(item_w + (size_t)ic * EMB_DIM + lane * 4);
        const f4 ivd = *reinterpret_cast<const f4*>(item_w + (size_t)id_ * EMB_DIM + lane * 4);

        float da = bf2f(ha.x & 0xFFFFu) * iva.x + bf2f(ha.x >> 16) * iva.y
                 + bf2f(ha.y & 0xFFFFu) * iva.z + bf2f(ha.y >> 16) * iva.w;
        float db = bf2f(hb.x & 0xFFFFu) * ivb.x + bf2f(hb.x >> 16) * ivb.y
                 + bf2f(hb.y & 0xFFFFu) * ivb.z + bf2f(hb.y >> 16) * ivb.w;
        float dc = bf2f(hc.x & 0xFFFFu) * ivc.x + bf2f(hc.x >> 16) * ivc.y
                 + bf2f(hc.y & 0xFFFFu) * ivc.z + bf2f(hc.y >> 16) * ivc.w;
        float dd = bf2f(hd.x & 0xFFFFu) * ivd.x + bf2f(hd.x >> 16) * ivd.y
                 + bf2f(hd.y & 0xFFFFu) * ivd.z + bf2f(hd.y >> 16) * ivd.w;

        da += __shfl_xor(da, 1); da += __shfl_xor(da, 2); da += __shfl_xor(da, 4); da += __shfl_xor(da, 8);
        db += __shfl_xor(db, 1); db += __shfl_xor(db, 2); db += __shfl_xor(db, 4); db += __shfl_xor(db, 8);
        dc += __shfl_xor(dc, 1); dc += __shfl_xor(dc, 2); dc += __shfl_xor(dc, 4); dc += __shfl_xor(dc, 8);
        dd += __shfl_xor(dd, 1); dd += __shfl_xor(dd, 2); dd += __shfl_xor(dd, 4); dd += __shfl_xor(dd, 8);

        if (lane == 0) {
            out[sa] = bias0 + da + freq_w[idx_emb[sa] * 32 + freq[sa]];
            out[sb] = bias0 + db + freq_w[idx_emb[sb] * 32 + freq[sb]];
            out[sc] = bias0 + dc + freq_w[idx_emb[sc] * 32 + freq[sc]];
            out[sd] = bias0 + dd + freq_w[idx_emb[sd] * 32 + freq[sd]];
        }
    }
    for (; s < B; s += stride) {
        const uint2 h = *reinterpret_cast<const uint2*>(user_h + (size_t)user[s] * EMB_DIM + lane * 4);
        const f4 vv = *reinterpret_cast<const f4*>(item_w + (size_t)item[s] * EMB_DIM + lane * 4);
        float d = bf2f(h.x & 0xFFFFu) * vv.x + bf2f(h.x >> 16) * vv.y
                + bf2f(h.y & 0xFFFFu) * vv.z + bf2f(h.y >> 16) * vv.w;
        d += __shfl_xor(d, 1); d += __shfl_xor(d, 2); d += __shfl_xor(d, 4); d += __shfl_xor(d, 8);
        if (lane == 0)
            out[s] = bias0 + d + freq_w[idx_emb[s] * 32 + freq[s]];
    }
}

// fallback: round-7 direct fp32 kernel (if workspace too small for bf16 table)
__global__ __launch_bounds__(256) void sfc_direct(
    const int* __restrict__ user, const int* __restrict__ item,
    const int* __restrict__ freq, const int* __restrict__ idx_emb,
    const float* __restrict__ bias_w, const float* __restrict__ user_w,
    const float* __restrict__ item_w, const float* __restrict__ freq_w,
    float* __restrict__ out, int B)
{
    const int group = threadIdx.x >> 4;
    const int lane = threadIdx.x & 15;
    const int stride = (gridDim.x * blockDim.x) >> 4;
    const float bias0 = bias_w[0];
    for (int s = blockIdx.x * 16 + group; s < B; s += stride) {
        const f4 uv = __builtin_nontemporal_load(
            reinterpret_cast<const f4*>(user_w + (size_t)user[s] * EMB_DIM + lane * 4));
        const f4 vv = *reinterpret_cast<const f4*>(item_w + (size_t)item[s] * EMB_DIM + lane * 4);
        float d = uv.x * vv.x + uv.y * vv.y + uv.z * vv.z + uv.w * vv.w;
        d += __shfl_xor(d, 1); d += __shfl_xor(d, 2); d += __shfl_xor(d, 4); d += __shfl_xor(d, 8);
        if (lane == 0)
            out[s] = bias0 + d + freq_w[idx_emb[s] * 32 + freq[s]];
    }
}

extern "C" void kernel_launch(void* const* d_in, const int* in_sizes, int n_in,
                              void* d_out, int out_size, void* d_ws, size_t ws_size,
                              hipStream_t stream) {
    const int B = in_sizes[0];
    const int*   user    = (const int*)d_in[0];
    const int*   item    = (const int*)d_in[1];
    const int*   freq    = (const int*)d_in[2];
    const int*   idx_emb = (const int*)d_in[3];
    // d_in[4] (zero) unused: all zeros, bias_w has one element.
    const float* bias_w  = (const float*)d_in[5];
    const float* user_w  = (const float*)d_in[6];
    const float* item_w  = (const float*)d_in[7];
    const float* freq_w  = (const float*)d_in[8];
    float* out = (float*)d_out;

    const int n_user_elems = in_sizes[6];              // 64,000,000
    const size_t need = (size_t)n_user_elems * sizeof(unsigned short);

    if (ws_size < need) {
        sfc_direct<<<2048, 256, 0, stream>>>(user, item, freq, idx_emb,
                                             bias_w, user_w, item_w, freq_w, out, B);
        return;
    }

    unsigned short* user_h = (unsigned short*)d_ws;
    k_cvt<<<2048, 256, 0, stream>>>(user_w, user_h, n_user_elems / 8);
    sfc_bf16<<<2048, 256, 0, stream>>>(user, item, freq, idx_emb,
                                       bias_w, user_h, item_w, freq_w, out, B);
}

// Round 9
// 166.463 us; speedup vs baseline: 1.1565x; 1.1565x over previous
//
#include <hip/hip_runtime.h>

// SFC model forward — direct gather at the random-request-rate ceiling.
//   out[b] = bias_w[0] + dot(user_w[user[b]], item_w[item[b]]) + freq_w[idx_emb[b], freq[b], 0]
//
// Final form (= round 7). Evidence r1-r8:
//  - random 256B user_w gathers are served at ~3.0-3.1 TB/s (~12.5G req/s)
//    regardless of structure (random / bucket-sorted / range-masked / nt);
//  - L2/L3 do not capture the ~2.3x duplicate reuse at full concurrency
//    (active window 8MB/XCD vs 4MB L2; L3 replacement streams it out);
//  - materialized reorders cost >=68us preprocess, > best-case saving;
//  - bf16 table compression halves bytes but NOT requests: gather pass
//    only dropped to ~130us while the mandatory per-launch fp32->bf16
//    conversion added ~60us (192.5us total, a net loss).
// Residual structure: zero[] never read (all zeros, bias_w is [1]),
// nontemporal user gathers (no reuse -> don't pollute L2/L3),
// 4x-unrolled grid-stride loop (8 gathers in flight per 16-lane group).

#define EMB_DIM 64

typedef float f4 __attribute__((ext_vector_type(4)));

__global__ __launch_bounds__(256) void sfc_fwd(
    const int* __restrict__ user, const int* __restrict__ item,
    const int* __restrict__ freq, const int* __restrict__ idx_emb,
    const float* __restrict__ bias_w, const float* __restrict__ user_w,
    const float* __restrict__ item_w, const float* __restrict__ freq_w,
    float* __restrict__ out, int B)
{
    const int group_in_block = threadIdx.x >> 4;   // 16 groups of 16 lanes
    const int lane = threadIdx.x & 15;
    const int stride = (gridDim.x * blockDim.x) >> 4;
    const int start = blockIdx.x * 16 + group_in_block;
    const float bias0 = bias_w[0];

    int s = start;
    for (; s + 3 * stride < B; s += 4 * stride) {
        const int sa = s, sb = s + stride, sc = s + 2 * stride, sd = s + 3 * stride;

        const int ua = user[sa], ub = user[sb], uc = user[sc], ud = user[sd];
        const int ia = item[sa], ib = item[sb], ic = item[sc], id_ = item[sd];

        // user rows: nontemporal (no reuse); item rows: cached (21x reuse)
        const f4 uva = __builtin_nontemporal_load(
            reinterpret_cast<const f4*>(user_w + (size_t)ua * EMB_DIM + lane * 4));
        const f4 uvb = __builtin_nontemporal_load(
            reinterpret_cast<const f4*>(user_w + (size_t)ub * EMB_DIM + lane * 4));
        const f4 uvc = __builtin_nontemporal_load(
            reinterpret_cast<const f4*>(user_w + (size_t)uc * EMB_DIM + lane * 4));
        const f4 uvd = __builtin_nontemporal_load(
            reinterpret_cast<const f4*>(user_w + (size_t)ud * EMB_DIM + lane * 4));
        const f4 iva = *reinterpret_cast<const f4*>(item_w + (size_t)ia * EMB_DIM + lane * 4);
        const f4 ivb = *reinterpret_cast<const f4*>(item_w + (size_t)ib * EMB_DIM + lane * 4);
        const f4 ivc = *reinterpret_cast<const f4*>(item_w + (size_t)ic * EMB_DIM + lane * 4);
        const f4 ivd = *reinterpret_cast<const f4*>(item_w + (size_t)id_ * EMB_DIM + lane * 4);

        float da = uva.x * iva.x + uva.y * iva.y + uva.z * iva.z + uva.w * iva.w;
        float db = uvb.x * ivb.x + uvb.y * ivb.y + uvb.z * ivb.z + uvb.w * ivb.w;
        float dc = uvc.x * ivc.x + uvc.y * ivc.y + uvc.z * ivc.z + uvc.w * ivc.w;
        float dd = uvd.x * ivd.x + uvd.y * ivd.y + uvd.z * ivd.z + uvd.w * ivd.w;

        da += __shfl_xor(da, 1); da += __shfl_xor(da, 2); da += __shfl_xor(da, 4); da += __shfl_xor(da, 8);
        db += __shfl_xor(db, 1); db += __shfl_xor(db, 2); db += __shfl_xor(db, 4); db += __shfl_xor(db, 8);
        dc += __shfl_xor(dc, 1); dc += __shfl_xor(dc, 2); dc += __shfl_xor(dc, 4); dc += __shfl_xor(dc, 8);
        dd += __shfl_xor(dd, 1); dd += __shfl_xor(dd, 2); dd += __shfl_xor(dd, 4); dd += __shfl_xor(dd, 8);

        if (lane == 0) {
            out[sa] = bias0 + da + freq_w[idx_emb[sa] * 32 + freq[sa]];
            out[sb] = bias0 + db + freq_w[idx_emb[sb] * 32 + freq[sb]];
            out[sc] = bias0 + dc + freq_w[idx_emb[sc] * 32 + freq[sc]];
            out[sd] = bias0 + dd + freq_w[idx_emb[sd] * 32 + freq[sd]];
        }
    }
    for (; s < B; s += stride) {
        const f4 uv = __builtin_nontemporal_load(
            reinterpret_cast<const f4*>(user_w + (size_t)user[s] * EMB_DIM + lane * 4));
        const f4 vv = *reinterpret_cast<const f4*>(item_w + (size_t)item[s] * EMB_DIM + lane * 4);
        float d = uv.x * vv.x + uv.y * vv.y + uv.z * vv.z + uv.w * vv.w;
        d += __shfl_xor(d, 1); d += __shfl_xor(d, 2); d += __shfl_xor(d, 4); d += __shfl_xor(d, 8);
        if (lane == 0)
            out[s] = bias0 + d + freq_w[idx_emb[s] * 32 + freq[s]];
    }
}

extern "C" void kernel_launch(void* const* d_in, const int* in_sizes, int n_in,
                              void* d_out, int out_size, void* d_ws, size_t ws_size,
                              hipStream_t stream) {
    const int B = in_sizes[0];
    const int*   user    = (const int*)d_in[0];
    const int*   item    = (const int*)d_in[1];
    const int*   freq    = (const int*)d_in[2];
    const int*   idx_emb = (const int*)d_in[3];
    // d_in[4] (zero) intentionally unused: all zeros, bias_w has one element.
    const float* bias_w  = (const float*)d_in[5];
    const float* user_w  = (const float*)d_in[6];
    const float* item_w  = (const float*)d_in[7];
    const float* freq_w  = (const float*)d_in[8];
    float* out = (float*)d_out;

    // 2048 blocks x 256 threads -> 8 blocks/CU (32 waves/CU, occupancy-max).
    sfc_fwd<<<2048, 256, 0, stream>>>(user, item, freq, idx_emb,
                                      bias_w, user_w, item_w, freq_w, out, B);
}